// Round 4
// baseline (17.352 us; speedup 1.0000x reference)
//
#include <hip/hip_runtime.h>

// HiddenMerger: the masked softmax's diagonal is exactly 0 for rows m>=1
// (diagonal masked with -2^32; exp underflows in fp32) and exactly 1/L for
// row 0 (every entry of row 0 rounds to exactly -2^32 -> uniform softmax).
//   out[b,0,d]    = (1/L) * sum_l hidden[b,l,d]
//   out[b,m>=1,d] = 0
// Single dispatch, 1024 blocks (4/CU -> 4 waves/SIMD for latency hiding):
//   blocks 0..127   : sum block (c,b) owns an 8-float4 (128 B) column slice,
//                     sums over all L rows (unroll 16), LDS-reduces 32 ways,
//                     writes its 128 B of row 0 scaled by 1/L.
//   blocks 128..1023: zero blocks, grid-stride over the 8188 (b,row>=1) rows,
//                     one coalesced 4 KB row store per iteration.

namespace {
constexpr int B = 4;
constexpr int L = 2048;
constexpr int D = 1024;
constexpr int D4 = D / 4;            // 256 float4 per row
constexpr int CI = 8;                // float4 columns per sum block (128 B)
constexpr int CHUNKS = D4 / CI;      // 32 column slices per batch
constexpr int WAYS = 256 / CI;       // 32 row-ways per sum block
constexpr int NSUM = CHUNKS * B;     // 128 sum blocks
constexpr int NZ = 896;              // zero blocks
constexpr int NROWS_Z = (L - 1) * B; // 8188 rows to zero
}

__global__ __launch_bounds__(256) void k_fused(const float* __restrict__ hidden,
                                               float* __restrict__ out) {
    const int bid = blockIdx.x;
    const int t = threadIdx.x;

    if (bid < NSUM) {
        // ---- sum role ----
        const int c = bid & (CHUNKS - 1);   // column slice 0..31
        const int b = bid >> 5;             // batch 0..3
        const int ci = t & (CI - 1);        // float4 column within slice
        const int ri = t >> 3;              // row-way 0..31
        const int colf4 = c * CI + ci;      // 0..255

        const float4* hp = reinterpret_cast<const float4*>(hidden + (size_t)b * L * D);
        float4 s = make_float4(0.f, 0.f, 0.f, 0.f);
#pragma unroll 16
        for (int r = ri; r < L; r += WAYS) {            // 64 iterations
            float4 v = hp[(size_t)r * D4 + colf4];
            s.x += v.x; s.y += v.y; s.z += v.z; s.w += v.w;
        }

        __shared__ float4 red[256];
        red[t] = s;
        __syncthreads();
#pragma unroll
        for (int sh = WAYS / 2; sh > 0; sh >>= 1) {     // 32 -> 1, fixed order
            if (ri < sh) {
                float4 o = red[(ri + sh) * CI + ci];
                float4 m = red[t];
                m.x += o.x; m.y += o.y; m.z += o.z; m.w += o.w;
                red[t] = m;
            }
            __syncthreads();
        }
        if (ri == 0) {
            float4 m = red[ci];
            const float sc = 1.0f / (float)L;           // 2^-11, exact
            m.x *= sc; m.y *= sc; m.z *= sc; m.w *= sc;
            reinterpret_cast<float4*>(out + (size_t)b * L * D)[colf4] = m;
        }
    } else {
        // ---- zero role: grid-stride over (b, row>=1) rows ----
        const int z = bid - NSUM;           // 0..NZ-1
        const float4 zero = make_float4(0.f, 0.f, 0.f, 0.f);
        for (int flat = z; flat < NROWS_Z; flat += NZ) {
            const int b = flat / (L - 1);
            const int row = 1 + flat % (L - 1);
            reinterpret_cast<float4*>(out + ((size_t)b * L + row) * D)[t] = zero;
        }
    }
}

extern "C" void kernel_launch(void* const* d_in, const int* in_sizes, int n_in,
                              void* d_out, int out_size, void* d_ws, size_t ws_size,
                              hipStream_t stream) {
    const float* hidden = (const float*)d_in[0];
    float* out = (float*)d_out;
    hipLaunchKernelGGL(k_fused, dim3(NSUM + NZ), dim3(256), 0, stream, hidden, out);
}